// Round 9
// baseline (428.150 us; speedup 1.0000x reference)
//
#include <hip/hip_runtime.h>
#include <hip/hip_bf16.h>

#define EPSV 1e-5f
#define TW 4    // waves per block
#define TPW 4   // points per wave-tile
#define SPD 76  // padded LDS row stride (shorts)

typedef __attribute__((ext_vector_type(8))) short s8v;
typedef __attribute__((ext_vector_type(4))) float f4v;

struct InP {
  const float *points, *features; const int* gidx;
  const float *Wq,*bq,*Wk,*bk,*Wv,*bv,*Wp,*b_p;
  const float *bnp_g,*bnp_b,*bnp_m,*bnp_v;
  const float *Wg1,*bg1,*bng_g,*bng_b,*bng_m,*bng_v;
  const float *Wg2,*bg2,*Wo,*bo;
  float* out; int N;
};
struct WS {
  unsigned short *qW1;                               // N x 64 bf16
  unsigned short *kvT;                               // N x 128 bf16 (k row | v row)
  unsigned short *WAf, *Wkf, *Wvf, *W1f, *W2f, *Wof; // 8 frags x 64 lanes x 8 bf16
  unsigned short *Wpf;                               // 4 frags x 64 x 8
  float *bq1F, *bpF;                                 // 64 fp32 each
};

__device__ __forceinline__ unsigned short f2bf(float x){
  __hip_bfloat16 h = __float2bfloat16(x);
  unsigned short u; __builtin_memcpy(&u, &h, 2); return u;
}
__device__ __forceinline__ float bf2f(unsigned short s){
  union{unsigned u; float f;} c; c.u = ((unsigned)s) << 16; return c.f;
}
__device__ __forceinline__ unsigned pk2(float x, float y){
  __hip_bfloat162 h = __float22bfloat162_rn(make_float2(x, y));
  unsigned u; __builtin_memcpy(&u, &h, 4); return u;
}
__device__ __forceinline__ s8v pack8(f4v x0, f4v x1){
  s8v r;
  ((unsigned*)&r)[0] = pk2(x0[0], x0[1]);
  ((unsigned*)&r)[1] = pk2(x0[2], x0[3]);
  ((unsigned*)&r)[2] = pk2(x1[0], x1[1]);
  ((unsigned*)&r)[3] = pk2(x1[2], x1[3]);
  return r;
}
// a' = p - k, both bf16x8, result bf16x8
__device__ __forceinline__ s8v sub8bf(s8v p, s8v k){
  s8v r;
  #pragma unroll
  for (int t = 0; t < 4; t++){
    float a0 = bf2f((unsigned short)p[2*t+0]) - bf2f((unsigned short)k[2*t+0]);
    float a1 = bf2f((unsigned short)p[2*t+1]) - bf2f((unsigned short)k[2*t+1]);
    ((unsigned*)&r)[t] = pk2(a0, a1);
  }
  return r;
}

// ---------------- prep: BN folds + B-fragment swizzles, PARALLEL ----------
__global__ void __launch_bounds__(256) prep_kernel(InP P, WS W){
  const int g = blockIdx.x*256 + threadIdx.x;   // 0..4095
  const int e = g >> 3, j = g & 7;              // e < 512
  const int f = e >> 6, L = e & 63;
  const int ks = f & 1, nt = f >> 1;
  const int n = nt*16 + (L & 15);
  const int k = ks*32 + ((L >> 4) << 3) + j;
  const float sg = P.bng_g[n] * rsqrtf(P.bng_v[n] + EPSV);
  W.W1f[e*8+j] = f2bf(P.Wg1[k*64+n] * sg);
  W.W2f[e*8+j] = f2bf(P.Wg2[k*64+n]);
  W.Wof[e*8+j] = f2bf(P.Wo [k*64+n]);
  W.Wkf[e*8+j] = f2bf(P.Wk [k*64+n]);
  W.Wvf[e*8+j] = f2bf(P.Wv [k*64+n]);
  float acc = 0.f;
  #pragma unroll 8
  for (int d = 0; d < 64; d++) acc += P.Wq[k*64+d] * P.Wg1[d*64+n];
  W.WAf[e*8+j] = f2bf(acc * sg);
  if (g < 2048){
    int ep = g >> 3;  // 0..255
    int ntp = ep >> 6, Lp = ep & 63;
    int np_ = ntp*16 + (Lp & 15);
    int kp = ((Lp >> 4) << 3) + j;
    float sp = P.bnp_g[np_] * rsqrtf(P.bnp_v[np_] + EPSV);
    W.Wpf[ep*8+j] = f2bf(kp < 3 ? P.Wp[kp*64+np_]*sp : 0.f);
  }
  if (g < 64){
    float sgt = P.bng_g[g] * rsqrtf(P.bng_v[g] + EPSV);
    float spt = P.bnp_g[g] * rsqrtf(P.bnp_v[g] + EPSV);
    float acc2 = 0.f;
    for (int d = 0; d < 64; d++) acc2 += P.bq[d] * P.Wg1[d*64+g];
    W.bq1F[g] = acc2*sgt + P.bg1[g]*sgt + P.bng_b[g] - P.bng_m[g]*sgt;
    W.bpF[g]  = P.b_p[g]*spt + P.bnp_b[g] - P.bnp_m[g]*spt;
  }
}

// ---------------- qkv: qW1 = f@(Wq@W1F)+bq1F ; kvT = [f@Wk+bk | f@Wv+bv] --
__global__ void __launch_bounds__(256) qkv_kernel(InP P, WS W){
  const int tid = threadIdx.x;
  const int wid = tid >> 6, l = tid & 63;
  const int cl = l & 15, q = l >> 4;
  const int TILES = (P.N + 15) >> 4;
  const int task = blockIdx.x * TW + wid;
  if (task >= TILES) return;
  const int i0 = task * 16;
  int row = i0 + cl; if (row > P.N - 1) row = P.N - 1;
  const float* fr = P.features + (size_t)row*64 + q*8;
  f4v x0 = *(const f4v*)fr;
  f4v x1 = *(const f4v*)(fr + 4);
  s8v fa0 = pack8(x0, x1);
  x0 = *(const f4v*)(fr + 32);
  x1 = *(const f4v*)(fr + 36);
  s8v fa1 = pack8(x0, x1);

  auto doMat = [&](const unsigned short* Bf_, const float* biasPtr,
                   unsigned short* outPtr, int stride){
    const s8v* Bf = (const s8v*)Bf_;
    #pragma unroll
    for (int nt = 0; nt < 4; nt++){
      float bn = biasPtr[nt*16 + cl];
      f4v ci = { bn, bn, bn, bn };
      f4v c = __builtin_amdgcn_mfma_f32_16x16x32_bf16(fa0, Bf[(2*nt+0)*64 + l], ci, 0, 0, 0);
      c = __builtin_amdgcn_mfma_f32_16x16x32_bf16(fa1, Bf[(2*nt+1)*64 + l], c, 0, 0, 0);
      #pragma unroll
      for (int r = 0; r < 4; r++){
        int rg = i0 + q*4 + r;
        if (rg < P.N) outPtr[(size_t)rg*stride + nt*16 + cl] = f2bf(c[r]);
      }
    }
  };
  doMat(W.WAf, W.bq1F, W.qW1,      64);
  doMat(W.Wkf, P.bk,   W.kvT,     128);
  doMat(W.Wvf, P.bv,   W.kvT + 64,128);
}

// ---------------- main: 4-point wave tiles, parity-dbuf Sp, unroll 2 ------
// Per-wave LDS (wave-private, no __syncthreads):
//   Sp  [2][16][SPD] bf16 : p / T transpose scratch, parity double-buffered
//   PreB[TPW][SPD] bf16   : pre rows for inline Wo epilogue
//   sI  [TPW*16] int      : tile neighbor indices
// v and k gathered at iteration start (consumed late: latency covered).
__global__ void __launch_bounds__(256, 5) main_kernel(InP P, WS W){
  __shared__ __align__(16) unsigned short Sp[TW][2][16*SPD];
  __shared__ __align__(16) unsigned short PreB[TW][TPW*SPD];
  __shared__ __align__(16) int sI[TW][TPW*16];
  const int tid = threadIdx.x;
  const int wid = tid >> 6, l = tid & 63;
  const int cl = l & 15, q = l >> 4;
  const int TILES = (P.N + TPW - 1) / TPW;
  const int task = blockIdx.x * TW + wid;
  if (task >= TILES) return;
  const int i0 = task * TPW;
  unsigned short* PreBw = PreB[wid];
  int* sIw = sI[wid];

  // cooperative neighbor-index stage (TPW*16 = 64 ints per tile, 1/lane)
  {
    long base = (long)i0*16 + l;
    long maxb = (long)P.N*16 - 1;
    if (base > maxb) base = maxb;
    sIw[l] = P.gidx[base];
  }

  // held B-frags: W1 (BN-folded), W2, Wp
  s8v w1f[8], w2f[8], wpf[4];
  {
    const s8v* W1p = (const s8v*)W.W1f;
    const s8v* W2p = (const s8v*)W.W2f;
    const s8v* Wpp = (const s8v*)W.Wpf;
    #pragma unroll
    for (int f = 0; f < 8; f++){ w1f[f] = W1p[f*64 + l]; w2f[f] = W2p[f*64 + l]; }
    #pragma unroll
    for (int f = 0; f < 4; f++) wpf[f] = Wpp[f*64 + l];
  }
  float bp4[4], b24[4];
  #pragma unroll
  for (int nt = 0; nt < 4; nt++){ bp4[nt] = W.bpF[nt*16 + cl]; b24[nt] = P.bg2[nt*16 + cl]; }

  // ---- prologue prefetch for pt = 0 (neighbor xyz, center xyz, qW1 row)
  float ngx=0.f, ngy=0.f, ngz=0.f;
  {
    int nidx = sIw[cl];
    if (l < 16){ const float* gp = P.points + (size_t)nidx*3; ngx=gp[0]; ngy=gp[1]; ngz=gp[2]; }
  }
  float ncx = P.points[(size_t)i0*3+0];
  float ncy = P.points[(size_t)i0*3+1];
  float ncz = P.points[(size_t)i0*3+2];
  float nq0, nq1, nq2, nq3;
  {
    const unsigned short* qr = W.qW1 + (size_t)i0*64;
    nq0 = bf2f(qr[cl]); nq1 = bf2f(qr[16+cl]); nq2 = bf2f(qr[32+cl]); nq3 = bf2f(qr[48+cl]);
  }

  #pragma unroll 2
  for (int pt = 0; pt < TPW; pt++){
    unsigned short* Spw = Sp[wid][pt & 1];

    // 0. issue k-frag gather for CURRENT point (consumed at phase 4)
    int kidx = sIw[pt*16 + cl];
    const s8v* kvp = (const s8v*)(W.kvT + (size_t)kidx*128);
    s8v gk0 = kvp[q], gk1 = kvp[4+q];

    // 1. issue v gathers for CURRENT point in C-layout (consumed in phase 8)
    unsigned short vv[16];
    {
      int4 vidx = *(const int4*)&sIw[pt*16 + q*4];
      #pragma unroll
      for (int r = 0; r < 4; r++){
        const unsigned short* vb = W.kvT + (size_t)vidx[r]*128 + 64 + cl;
        #pragma unroll
        for (int nt = 0; nt < 4; nt++) vv[nt*4+r] = vb[nt*16];
      }
    }

    // rotate prefetch -> current
    float gx=ngx, gy=ngy, gz=ngz, cx=ncx, cy=ncy, cz=ncz;
    float qc0=nq0, qc1=nq1, qc2=nq2, qc3=nq3;
    const bool valid = (i0 + pt < P.N);

    // 2. p = relu(rel @ WpF + bpF), write to Sp (C-layout, bf16 scalar)
    s8v ap;
    ((unsigned*)&ap)[0] = pk2(gx-cx, gy-cy);
    ((unsigned*)&ap)[1] = pk2(gz-cz, 0.f);
    ((unsigned*)&ap)[2] = 0u; ((unsigned*)&ap)[3] = 0u;
    f4v pc[4];
    #pragma unroll
    for (int nt = 0; nt < 4; nt++){
      f4v ci = { bp4[nt], bp4[nt], bp4[nt], bp4[nt] };
      pc[nt] = __builtin_amdgcn_mfma_f32_16x16x32_bf16(ap, wpf[nt], ci, 0, 0, 0);
    }
    unsigned pcp[8];   // p packed bf16 (register-pressure relief)
    #pragma unroll
    for (int nt = 0; nt < 4; nt++){
      #pragma unroll
      for (int r = 0; r < 4; r++){
        pc[nt][r] = fmaxf(pc[nt][r], 0.f);
        Spw[(q*4+r)*SPD + nt*16 + cl] = f2bf(pc[nt][r]);
      }
      pcp[nt*2+0] = pk2(pc[nt][0], pc[nt][1]);
      pcp[nt*2+1] = pk2(pc[nt][2], pc[nt][3]);
    }

    // 3. prefetch pt+1 xyz/center/qW1 (wraps harmlessly at pt=TPW-1)
    {
      int np = (pt + 1) & (TPW-1);
      int nidx = sIw[np*16 + cl];
      if (l < 16){ const float* gp = P.points + (size_t)nidx*3; ngx=gp[0]; ngy=gp[1]; ngz=gp[2]; }
      int ii = i0 + np; if (ii > P.N - 1) ii = P.N - 1;
      ncx = P.points[(size_t)ii*3+0];
      ncy = P.points[(size_t)ii*3+1];
      ncz = P.points[(size_t)ii*3+2];
      const unsigned short* qr = W.qW1 + (size_t)ii*64;
      nq0 = bf2f(qr[cl]); nq1 = bf2f(qr[16+cl]); nq2 = bf2f(qr[32+cl]); nq3 = bf2f(qr[48+cl]);
    }

    // 4. a' = p - gk (A-layout read of bf16 p, bf16 subtract)
    s8v af0, af1;
    {
      s8v p0 = *(const s8v*)&Spw[cl*SPD + q*8];
      s8v p1 = *(const s8v*)&Spw[cl*SPD + 32 + q*8];
      af0 = sub8bf(p0, gk0);
      af1 = sub8bf(p1, gk1);
    }

    // 5. T = relu(a' @ W1F + qW1row)
    f4v tc[4];
    #pragma unroll
    for (int nt = 0; nt < 4; nt++){
      float qcn = (nt==0) ? qc0 : (nt==1) ? qc1 : (nt==2) ? qc2 : qc3;
      f4v ci = { qcn, qcn, qcn, qcn };
      tc[nt] = __builtin_amdgcn_mfma_f32_16x16x32_bf16(af0, w1f[2*nt+0], ci, 0, 0, 0);
      tc[nt] = __builtin_amdgcn_mfma_f32_16x16x32_bf16(af1, w1f[2*nt+1], tc[nt], 0, 0, 0);
      #pragma unroll
      for (int r = 0; r < 4; r++) tc[nt][r] = fmaxf(tc[nt][r], 0.f);
    }

    // 6. T -> Sp (bf16 scalar C-write), read back directly as A-frags
    #pragma unroll
    for (int nt = 0; nt < 4; nt++)
      #pragma unroll
      for (int r = 0; r < 4; r++)
        Spw[(q*4+r)*SPD + nt*16 + cl] = f2bf(tc[nt][r]);
    s8v tf0 = *(const s8v*)&Spw[cl*SPD + q*8];
    s8v tf1 = *(const s8v*)&Spw[cl*SPD + 32 + q*8];

    // 7. H = T @ W2 + b2
    f4v hc[4];
    #pragma unroll
    for (int nt = 0; nt < 4; nt++){
      f4v ci = { b24[nt], b24[nt], b24[nt], b24[nt] };
      hc[nt] = __builtin_amdgcn_mfma_f32_16x16x32_bf16(tf0, w2f[2*nt+0], ci, 0, 0, 0);
      hc[nt] = __builtin_amdgcn_mfma_f32_16x16x32_bf16(tf1, w2f[2*nt+1], hc[nt], 0, 0, 0);
    }

    // 8. softmax over 16 neighbor rows (no max-shift: |h| small, exp safe)
    //    + weighted sum of (v+p)
    float pre4[4];
    #pragma unroll
    for (int nt = 0; nt < 4; nt++){
      float p01lo = bf2f((unsigned short)(pcp[nt*2+0] & 0xffff));
      float p01hi = bf2f((unsigned short)(pcp[nt*2+0] >> 16));
      float p23lo = bf2f((unsigned short)(pcp[nt*2+1] & 0xffff));
      float p23hi = bf2f((unsigned short)(pcp[nt*2+1] >> 16));
      float pv[4] = { p01lo, p01hi, p23lo, p23hi };
      float s = 0.f, acc = 0.f;
      #pragma unroll
      for (int r = 0; r < 4; r++){
        float e2 = __expf(hc[nt][r]);
        s += e2;
        acc = fmaf(e2, bf2f(vv[nt*4+r]) + pv[r], acc);
      }
      s += __shfl_xor(s, 16, 64);
      s += __shfl_xor(s, 32, 64);
      acc += __shfl_xor(acc, 16, 64);
      acc += __shfl_xor(acc, 32, 64);
      pre4[nt] = acc * __builtin_amdgcn_rcpf(s);
    }
    if (valid){
      float sa = (l & 16) ? pre4[1] : pre4[0];
      float sb = (l & 16) ? pre4[3] : pre4[2];
      PreBw[pt*SPD + l] = f2bf((l & 32) ? sb : sa);
    }
  }

  // inline epilogue: out rows = PreB(4x64) @ Wo + bo (rows 4..15 duplicated,
  // discarded by the store guard)
  s8v wof[8];
  {
    const s8v* Wop = (const s8v*)W.Wof;
    #pragma unroll
    for (int f = 0; f < 8; f++) wof[f] = Wop[f*64 + l];
  }
  s8v ef0 = *(const s8v*)&PreBw[(cl & (TPW-1))*SPD + q*8];
  s8v ef1 = *(const s8v*)&PreBw[(cl & (TPW-1))*SPD + 32 + q*8];
  #pragma unroll
  for (int nt = 0; nt < 4; nt++){
    float bn = P.bo[nt*16 + cl];
    f4v ci = { bn, bn, bn, bn };
    f4v oc = __builtin_amdgcn_mfma_f32_16x16x32_bf16(ef0, wof[2*nt+0], ci, 0, 0, 0);
    oc = __builtin_amdgcn_mfma_f32_16x16x32_bf16(ef1, wof[2*nt+1], oc, 0, 0, 0);
    #pragma unroll
    for (int r = 0; r < 4; r++){
      int ro = q*4 + r;
      int rg = i0 + ro;
      if (ro < TPW && rg < P.N) P.out[(size_t)rg*64 + nt*16 + cl] = oc[r];
    }
  }
}

extern "C" void kernel_launch(void* const* d_in, const int* in_sizes, int n_in,
                              void* d_out, int out_size, void* d_ws, size_t ws_size,
                              hipStream_t stream){
  InP P;
  P.points   = (const float*)d_in[0];
  P.features = (const float*)d_in[1];
  P.gidx     = (const int*)d_in[2];
  P.Wq  = (const float*)d_in[3];  P.bq  = (const float*)d_in[4];
  P.Wk  = (const float*)d_in[5];  P.bk  = (const float*)d_in[6];
  P.Wv  = (const float*)d_in[7];  P.bv  = (const float*)d_in[8];
  P.Wp  = (const float*)d_in[9];  P.b_p = (const float*)d_in[10];
  P.bnp_g = (const float*)d_in[11]; P.bnp_b = (const float*)d_in[12];
  P.bnp_m = (const float*)d_in[13]; P.bnp_v = (const float*)d_in[14];
  P.Wg1 = (const float*)d_in[15]; P.bg1 = (const float*)d_in[16];
  P.bng_g = (const float*)d_in[17]; P.bng_b = (const float*)d_in[18];
  P.bng_m = (const float*)d_in[19]; P.bng_v = (const float*)d_in[20];
  P.Wg2 = (const float*)d_in[21]; P.bg2 = (const float*)d_in[22];
  P.Wo  = (const float*)d_in[23]; P.bo  = (const float*)d_in[24];
  P.out = (float*)d_out;
  const int N = in_sizes[0] / 3;
  P.N = N;

  WS W;
  char* w = (char*)d_ws;
  W.qW1 = (unsigned short*)w; w += (size_t)N*64*2;
  W.kvT = (unsigned short*)w; w += (size_t)N*128*2;
  W.WAf = (unsigned short*)w; w += 8*64*8*2;
  W.Wkf = (unsigned short*)w; w += 8*64*8*2;
  W.Wvf = (unsigned short*)w; w += 8*64*8*2;
  W.W1f = (unsigned short*)w; w += 8*64*8*2;
  W.W2f = (unsigned short*)w; w += 8*64*8*2;
  W.Wof = (unsigned short*)w; w += 8*64*8*2;
  W.Wpf = (unsigned short*)w; w += 4*64*8*2;
  W.bq1F = (float*)w; w += 256;
  W.bpF  = (float*)w; w += 256;

  const int TILES16 = (N + 15) / 16;
  const int grid16 = (TILES16 + TW - 1) / TW;
  const int TILESM = (N + TPW - 1) / TPW;
  const int gridM = (TILESM + TW - 1) / TW;
  hipLaunchKernelGGL(prep_kernel, dim3(16),     dim3(256), 0, stream, P, W);
  hipLaunchKernelGGL(qkv_kernel,  dim3(grid16), dim3(256), 0, stream, P, W);
  hipLaunchKernelGGL(main_kernel, dim3(gridM),  dim3(256), 0, stream, P, W);
}

// Round 10
// 208.993 us; speedup vs baseline: 2.0486x; 2.0486x over previous
//
#include <hip/hip_runtime.h>
#include <hip/hip_bf16.h>

#define EPSV 1e-5f
#define TW 4    // waves per block
#define TPW 4   // points per wave-tile
#define SPD 76  // padded LDS row stride (shorts)

typedef __attribute__((ext_vector_type(8))) short s8v;
typedef __attribute__((ext_vector_type(4))) float f4v;

struct InP {
  const float *points, *features; const int* gidx;
  const float *Wq,*bq,*Wk,*bk,*Wv,*bv,*Wp,*b_p;
  const float *bnp_g,*bnp_b,*bnp_m,*bnp_v;
  const float *Wg1,*bg1,*bng_g,*bng_b,*bng_m,*bng_v;
  const float *Wg2,*bg2,*Wo,*bo;
  float* out; int N;
};
struct WS {
  unsigned short *qW1;                               // N x 64 bf16
  unsigned short *kvT;                               // N x 128 bf16 (k row | v row)
  unsigned short *WAf, *Wkf, *Wvf, *W1f, *W2f, *Wof; // 8 frags x 64 lanes x 8 bf16
  unsigned short *Wpf;                               // 4 frags x 64 x 8
  float *bq1F, *bpF;                                 // 64 fp32 each
};

__device__ __forceinline__ unsigned short f2bf(float x){
  __hip_bfloat16 h = __float2bfloat16(x);
  unsigned short u; __builtin_memcpy(&u, &h, 2); return u;
}
__device__ __forceinline__ float bf2f(unsigned short s){
  union{unsigned u; float f;} c; c.u = ((unsigned)s) << 16; return c.f;
}
__device__ __forceinline__ unsigned pk2(float x, float y){
  __hip_bfloat162 h = __float22bfloat162_rn(make_float2(x, y));
  unsigned u; __builtin_memcpy(&u, &h, 4); return u;
}
__device__ __forceinline__ s8v pack8(f4v x0, f4v x1){
  s8v r;
  ((unsigned*)&r)[0] = pk2(x0[0], x0[1]);
  ((unsigned*)&r)[1] = pk2(x0[2], x0[3]);
  ((unsigned*)&r)[2] = pk2(x1[0], x1[1]);
  ((unsigned*)&r)[3] = pk2(x1[2], x1[3]);
  return r;
}
// a' = p - k, both bf16x8, result bf16x8
__device__ __forceinline__ s8v sub8bf(s8v p, s8v k){
  s8v r;
  #pragma unroll
  for (int t = 0; t < 4; t++){
    float a0 = bf2f((unsigned short)p[2*t+0]) - bf2f((unsigned short)k[2*t+0]);
    float a1 = bf2f((unsigned short)p[2*t+1]) - bf2f((unsigned short)k[2*t+1]);
    ((unsigned*)&r)[t] = pk2(a0, a1);
  }
  return r;
}

// ---------------- prep: BN folds + B-fragment swizzles, PARALLEL ----------
__global__ void __launch_bounds__(256) prep_kernel(InP P, WS W){
  const int g = blockIdx.x*256 + threadIdx.x;   // 0..4095
  const int e = g >> 3, j = g & 7;              // e < 512
  const int f = e >> 6, L = e & 63;
  const int ks = f & 1, nt = f >> 1;
  const int n = nt*16 + (L & 15);
  const int k = ks*32 + ((L >> 4) << 3) + j;
  const float sg = P.bng_g[n] * rsqrtf(P.bng_v[n] + EPSV);
  W.W1f[e*8+j] = f2bf(P.Wg1[k*64+n] * sg);
  W.W2f[e*8+j] = f2bf(P.Wg2[k*64+n]);
  W.Wof[e*8+j] = f2bf(P.Wo [k*64+n]);
  W.Wkf[e*8+j] = f2bf(P.Wk [k*64+n]);
  W.Wvf[e*8+j] = f2bf(P.Wv [k*64+n]);
  float acc = 0.f;
  #pragma unroll 8
  for (int d = 0; d < 64; d++) acc += P.Wq[k*64+d] * P.Wg1[d*64+n];
  W.WAf[e*8+j] = f2bf(acc * sg);
  if (g < 2048){
    int ep = g >> 3;  // 0..255
    int ntp = ep >> 6, Lp = ep & 63;
    int np_ = ntp*16 + (Lp & 15);
    int kp = ((Lp >> 4) << 3) + j;
    float sp = P.bnp_g[np_] * rsqrtf(P.bnp_v[np_] + EPSV);
    W.Wpf[ep*8+j] = f2bf(kp < 3 ? P.Wp[kp*64+np_]*sp : 0.f);
  }
  if (g < 64){
    float sgt = P.bng_g[g] * rsqrtf(P.bng_v[g] + EPSV);
    float spt = P.bnp_g[g] * rsqrtf(P.bnp_v[g] + EPSV);
    float acc2 = 0.f;
    for (int d = 0; d < 64; d++) acc2 += P.bq[d] * P.Wg1[d*64+g];
    W.bq1F[g] = acc2*sgt + P.bg1[g]*sgt + P.bng_b[g] - P.bng_m[g]*sgt;
    W.bpF[g]  = P.b_p[g]*spt + P.bnp_b[g] - P.bnp_m[g]*spt;
  }
}

// ---------------- qkv: qW1 = f@(Wq@W1F)+bq1F ; kvT = [f@Wk+bk | f@Wv+bv] --
__global__ void __launch_bounds__(256) qkv_kernel(InP P, WS W){
  const int tid = threadIdx.x;
  const int wid = tid >> 6, l = tid & 63;
  const int cl = l & 15, q = l >> 4;
  const int TILES = (P.N + 15) >> 4;
  const int task = blockIdx.x * TW + wid;
  if (task >= TILES) return;
  const int i0 = task * 16;
  int row = i0 + cl; if (row > P.N - 1) row = P.N - 1;
  const float* fr = P.features + (size_t)row*64 + q*8;
  f4v x0 = *(const f4v*)fr;
  f4v x1 = *(const f4v*)(fr + 4);
  s8v fa0 = pack8(x0, x1);
  x0 = *(const f4v*)(fr + 32);
  x1 = *(const f4v*)(fr + 36);
  s8v fa1 = pack8(x0, x1);

  auto doMat = [&](const unsigned short* Bf_, const float* biasPtr,
                   unsigned short* outPtr, int stride){
    const s8v* Bf = (const s8v*)Bf_;
    #pragma unroll
    for (int nt = 0; nt < 4; nt++){
      float bn = biasPtr[nt*16 + cl];
      f4v ci = { bn, bn, bn, bn };
      f4v c = __builtin_amdgcn_mfma_f32_16x16x32_bf16(fa0, Bf[(2*nt+0)*64 + l], ci, 0, 0, 0);
      c = __builtin_amdgcn_mfma_f32_16x16x32_bf16(fa1, Bf[(2*nt+1)*64 + l], c, 0, 0, 0);
      #pragma unroll
      for (int r = 0; r < 4; r++){
        int rg = i0 + q*4 + r;
        if (rg < P.N) outPtr[(size_t)rg*stride + nt*16 + cl] = f2bf(c[r]);
      }
    }
  };
  doMat(W.WAf, W.bq1F, W.qW1,      64);
  doMat(W.Wkf, P.bk,   W.kvT,     128);
  doMat(W.Wvf, P.bv,   W.kvT + 64,128);
}

// ---------------- main: 4-point wave tiles, parity-dbuf Sp, unroll 2 ------
// Per-wave LDS (wave-private, no __syncthreads):
//   Sp  [2][16][SPD] bf16 : p / T transpose scratch, parity double-buffered
//   PreB[TPW][SPD] bf16   : pre rows for inline Wo epilogue
//   sI  [TPW*16] int      : tile neighbor indices
// v gathered directly in C-layout via scalar global loads (L1-hot rows).
// NOTE (R9 lesson): do NOT force min-waves>2 — natural VGPR ~112; forcing
// below 96 spills catastrophically (WRITE_SIZE 12.5 -> 397 MB).
__global__ void __launch_bounds__(256, 2) main_kernel(InP P, WS W){
  __shared__ __align__(16) unsigned short Sp[TW][2][16*SPD];
  __shared__ __align__(16) unsigned short PreB[TW][TPW*SPD];
  __shared__ __align__(16) int sI[TW][TPW*16];
  const int tid = threadIdx.x;
  const int wid = tid >> 6, l = tid & 63;
  const int cl = l & 15, q = l >> 4;
  const int TILES = (P.N + TPW - 1) / TPW;
  const int task = blockIdx.x * TW + wid;
  if (task >= TILES) return;
  const int i0 = task * TPW;
  unsigned short* PreBw = PreB[wid];
  int* sIw = sI[wid];

  // cooperative neighbor-index stage (TPW*16 = 64 ints per tile, 1/lane)
  {
    long base = (long)i0*16 + l;
    long maxb = (long)P.N*16 - 1;
    if (base > maxb) base = maxb;
    sIw[l] = P.gidx[base];
  }

  // held B-frags: W1 (BN-folded), W2, Wp
  s8v w1f[8], w2f[8], wpf[4];
  {
    const s8v* W1p = (const s8v*)W.W1f;
    const s8v* W2p = (const s8v*)W.W2f;
    const s8v* Wpp = (const s8v*)W.Wpf;
    #pragma unroll
    for (int f = 0; f < 8; f++){ w1f[f] = W1p[f*64 + l]; w2f[f] = W2p[f*64 + l]; }
    #pragma unroll
    for (int f = 0; f < 4; f++) wpf[f] = Wpp[f*64 + l];
  }
  float bp4[4], b24[4];
  #pragma unroll
  for (int nt = 0; nt < 4; nt++){ bp4[nt] = W.bpF[nt*16 + cl]; b24[nt] = P.bg2[nt*16 + cl]; }

  // ---- prologue prefetch for pt = 0 (k frags, neighbor xyz, center, qW1)
  int nidx = sIw[cl];
  s8v ngk0, ngk1;
  {
    const s8v* kv = (const s8v*)(W.kvT + (size_t)nidx*128);
    ngk0 = kv[q]; ngk1 = kv[4+q];
  }
  float ngx=0.f, ngy=0.f, ngz=0.f;
  if (l < 16){ const float* gp = P.points + (size_t)nidx*3; ngx=gp[0]; ngy=gp[1]; ngz=gp[2]; }
  float ncx = P.points[(size_t)i0*3+0];
  float ncy = P.points[(size_t)i0*3+1];
  float ncz = P.points[(size_t)i0*3+2];
  float nq0, nq1, nq2, nq3;
  {
    const unsigned short* qr = W.qW1 + (size_t)i0*64;
    nq0 = bf2f(qr[cl]); nq1 = bf2f(qr[16+cl]); nq2 = bf2f(qr[32+cl]); nq3 = bf2f(qr[48+cl]);
  }

  #pragma unroll 2
  for (int pt = 0; pt < TPW; pt++){
    unsigned short* Spw = Sp[wid][pt & 1];
    // rotate prefetch -> current
    s8v gk0=ngk0, gk1=ngk1;
    float gx=ngx, gy=ngy, gz=ngz, cx=ncx, cy=ncy, cz=ncz;
    float qc0=nq0, qc1=nq1, qc2=nq2, qc3=nq3;
    const bool valid = (i0 + pt < P.N);

    // 1. issue v gathers for CURRENT point in C-layout (consumed in phase 8)
    unsigned short vv[16];
    {
      int4 vidx = *(const int4*)&sIw[pt*16 + q*4];
      #pragma unroll
      for (int r = 0; r < 4; r++){
        const unsigned short* vb = W.kvT + (size_t)vidx[r]*128 + 64 + cl;
        #pragma unroll
        for (int nt = 0; nt < 4; nt++) vv[nt*4+r] = vb[nt*16];
      }
    }

    // 2. p = relu(rel @ WpF + bpF), write to Sp (C-layout, bf16 scalar)
    s8v ap;
    ((unsigned*)&ap)[0] = pk2(gx-cx, gy-cy);
    ((unsigned*)&ap)[1] = pk2(gz-cz, 0.f);
    ((unsigned*)&ap)[2] = 0u; ((unsigned*)&ap)[3] = 0u;
    f4v pc[4];
    #pragma unroll
    for (int nt = 0; nt < 4; nt++){
      f4v ci = { bp4[nt], bp4[nt], bp4[nt], bp4[nt] };
      pc[nt] = __builtin_amdgcn_mfma_f32_16x16x32_bf16(ap, wpf[nt], ci, 0, 0, 0);
    }
    #pragma unroll
    for (int nt = 0; nt < 4; nt++){
      #pragma unroll
      for (int r = 0; r < 4; r++){
        pc[nt][r] = fmaxf(pc[nt][r], 0.f);
        Spw[(q*4+r)*SPD + nt*16 + cl] = f2bf(pc[nt][r]);
      }
    }

    // 3. prefetch pt+1 (wraps harmlessly at pt=TPW-1)
    {
      int np = (pt + 1) & (TPW-1);
      nidx = sIw[np*16 + cl];
      const s8v* kv = (const s8v*)(W.kvT + (size_t)nidx*128);
      ngk0 = kv[q]; ngk1 = kv[4+q];
      if (l < 16){ const float* gp = P.points + (size_t)nidx*3; ngx=gp[0]; ngy=gp[1]; ngz=gp[2]; }
      int ii = i0 + np; if (ii > P.N - 1) ii = P.N - 1;
      ncx = P.points[(size_t)ii*3+0];
      ncy = P.points[(size_t)ii*3+1];
      ncz = P.points[(size_t)ii*3+2];
      const unsigned short* qr = W.qW1 + (size_t)ii*64;
      nq0 = bf2f(qr[cl]); nq1 = bf2f(qr[16+cl]); nq2 = bf2f(qr[32+cl]); nq3 = bf2f(qr[48+cl]);
    }

    // 4. a' = p - gk (A-layout read of bf16 p, bf16 subtract)
    s8v af0, af1;
    {
      s8v p0 = *(const s8v*)&Spw[cl*SPD + q*8];
      s8v p1 = *(const s8v*)&Spw[cl*SPD + 32 + q*8];
      af0 = sub8bf(p0, gk0);
      af1 = sub8bf(p1, gk1);
    }

    // 5. T = relu(a' @ W1F + qW1row)
    f4v tc[4];
    #pragma unroll
    for (int nt = 0; nt < 4; nt++){
      float qcn = (nt==0) ? qc0 : (nt==1) ? qc1 : (nt==2) ? qc2 : qc3;
      f4v ci = { qcn, qcn, qcn, qcn };
      tc[nt] = __builtin_amdgcn_mfma_f32_16x16x32_bf16(af0, w1f[2*nt+0], ci, 0, 0, 0);
      tc[nt] = __builtin_amdgcn_mfma_f32_16x16x32_bf16(af1, w1f[2*nt+1], tc[nt], 0, 0, 0);
      #pragma unroll
      for (int r = 0; r < 4; r++) tc[nt][r] = fmaxf(tc[nt][r], 0.f);
    }

    // 6. T -> Sp (bf16 scalar C-write), read back directly as A-frags
    #pragma unroll
    for (int nt = 0; nt < 4; nt++)
      #pragma unroll
      for (int r = 0; r < 4; r++)
        Spw[(q*4+r)*SPD + nt*16 + cl] = f2bf(tc[nt][r]);
    s8v tf0 = *(const s8v*)&Spw[cl*SPD + q*8];
    s8v tf1 = *(const s8v*)&Spw[cl*SPD + 32 + q*8];

    // 7. H = T @ W2 + b2
    f4v hc[4];
    #pragma unroll
    for (int nt = 0; nt < 4; nt++){
      f4v ci = { b24[nt], b24[nt], b24[nt], b24[nt] };
      hc[nt] = __builtin_amdgcn_mfma_f32_16x16x32_bf16(tf0, w2f[2*nt+0], ci, 0, 0, 0);
      hc[nt] = __builtin_amdgcn_mfma_f32_16x16x32_bf16(tf1, w2f[2*nt+1], hc[nt], 0, 0, 0);
    }

    // 8. softmax over 16 neighbor rows (no max-shift: |h| small, exp safe)
    //    + weighted sum of (v+p)
    float pre4[4];
    #pragma unroll
    for (int nt = 0; nt < 4; nt++){
      float s = 0.f, acc = 0.f;
      #pragma unroll
      for (int r = 0; r < 4; r++){
        float e2 = __expf(hc[nt][r]);
        s += e2;
        acc = fmaf(e2, bf2f(vv[nt*4+r]) + pc[nt][r], acc);
      }
      s += __shfl_xor(s, 16, 64);
      s += __shfl_xor(s, 32, 64);
      acc += __shfl_xor(acc, 16, 64);
      acc += __shfl_xor(acc, 32, 64);
      pre4[nt] = acc * __builtin_amdgcn_rcpf(s);
    }
    if (valid){
      float sa = (l & 16) ? pre4[1] : pre4[0];
      float sb = (l & 16) ? pre4[3] : pre4[2];
      PreBw[pt*SPD + l] = f2bf((l & 32) ? sb : sa);
    }
  }

  // inline epilogue: out rows = PreB(4x64) @ Wo + bo (rows 4..15 duplicated,
  // discarded by the store guard)
  s8v wof[8];
  {
    const s8v* Wop = (const s8v*)W.Wof;
    #pragma unroll
    for (int f = 0; f < 8; f++) wof[f] = Wop[f*64 + l];
  }
  s8v ef0 = *(const s8v*)&PreBw[(cl & (TPW-1))*SPD + q*8];
  s8v ef1 = *(const s8v*)&PreBw[(cl & (TPW-1))*SPD + 32 + q*8];
  #pragma unroll
  for (int nt = 0; nt < 4; nt++){
    float bn = P.bo[nt*16 + cl];
    f4v ci = { bn, bn, bn, bn };
    f4v oc = __builtin_amdgcn_mfma_f32_16x16x32_bf16(ef0, wof[2*nt+0], ci, 0, 0, 0);
    oc = __builtin_amdgcn_mfma_f32_16x16x32_bf16(ef1, wof[2*nt+1], oc, 0, 0, 0);
    #pragma unroll
    for (int r = 0; r < 4; r++){
      int ro = q*4 + r;
      int rg = i0 + ro;
      if (ro < TPW && rg < P.N) P.out[(size_t)rg*64 + nt*16 + cl] = oc[r];
    }
  }
}

extern "C" void kernel_launch(void* const* d_in, const int* in_sizes, int n_in,
                              void* d_out, int out_size, void* d_ws, size_t ws_size,
                              hipStream_t stream){
  InP P;
  P.points   = (const float*)d_in[0];
  P.features = (const float*)d_in[1];
  P.gidx     = (const int*)d_in[2];
  P.Wq  = (const float*)d_in[3];  P.bq  = (const float*)d_in[4];
  P.Wk  = (const float*)d_in[5];  P.bk  = (const float*)d_in[6];
  P.Wv  = (const float*)d_in[7];  P.bv  = (const float*)d_in[8];
  P.Wp  = (const float*)d_in[9];  P.b_p = (const float*)d_in[10];
  P.bnp_g = (const float*)d_in[11]; P.bnp_b = (const float*)d_in[12];
  P.bnp_m = (const float*)d_in[13]; P.bnp_v = (const float*)d_in[14];
  P.Wg1 = (const float*)d_in[15]; P.bg1 = (const float*)d_in[16];
  P.bng_g = (const float*)d_in[17]; P.bng_b = (const float*)d_in[18];
  P.bng_m = (const float*)d_in[19]; P.bng_v = (const float*)d_in[20];
  P.Wg2 = (const float*)d_in[21]; P.bg2 = (const float*)d_in[22];
  P.Wo  = (const float*)d_in[23]; P.bo  = (const float*)d_in[24];
  P.out = (float*)d_out;
  const int N = in_sizes[0] / 3;
  P.N = N;

  WS W;
  char* w = (char*)d_ws;
  W.qW1 = (unsigned short*)w; w += (size_t)N*64*2;
  W.kvT = (unsigned short*)w; w += (size_t)N*128*2;
  W.WAf = (unsigned short*)w; w += 8*64*8*2;
  W.Wkf = (unsigned short*)w; w += 8*64*8*2;
  W.Wvf = (unsigned short*)w; w += 8*64*8*2;
  W.W1f = (unsigned short*)w; w += 8*64*8*2;
  W.W2f = (unsigned short*)w; w += 8*64*8*2;
  W.Wof = (unsigned short*)w; w += 8*64*8*2;
  W.Wpf = (unsigned short*)w; w += 4*64*8*2;
  W.bq1F = (float*)w; w += 256;
  W.bpF  = (float*)w; w += 256;

  const int TILES16 = (N + 15) / 16;
  const int grid16 = (TILES16 + TW - 1) / TW;
  const int TILESM = (N + TPW - 1) / TPW;
  const int gridM = (TILESM + TW - 1) / TW;
  hipLaunchKernelGGL(prep_kernel, dim3(16),     dim3(256), 0, stream, P, W);
  hipLaunchKernelGGL(qkv_kernel,  dim3(grid16), dim3(256), 0, stream, P, W);
  hipLaunchKernelGGL(main_kernel, dim3(gridM),  dim3(256), 0, stream, P, W);
}

// Round 11
// 204.144 us; speedup vs baseline: 2.0973x; 1.0238x over previous
//
#include <hip/hip_runtime.h>
#include <hip/hip_bf16.h>

#define EPSV 1e-5f
#define TW 4    // waves per block
#define TPW 8   // points per wave-tile
#define SPD 76  // padded LDS row stride (shorts)

typedef __attribute__((ext_vector_type(8))) short s8v;
typedef __attribute__((ext_vector_type(4))) float f4v;

struct InP {
  const float *points, *features; const int* gidx;
  const float *Wq,*bq,*Wk,*bk,*Wv,*bv,*Wp,*b_p;
  const float *bnp_g,*bnp_b,*bnp_m,*bnp_v;
  const float *Wg1,*bg1,*bng_g,*bng_b,*bng_m,*bng_v;
  const float *Wg2,*bg2,*Wo,*bo;
  float* out; int N;
};
struct WS {
  unsigned short *qW1;                               // N x 64 bf16 (q@W1F + b1F)
  unsigned short *kvT;                               // N x 128 bf16 (kW1 row | v row)
  unsigned short *WAf, *Wkf, *Wvf, *W1f, *W2f, *Wof; // 8 frags x 64 lanes x 8 bf16
  unsigned short *Wpf;                               // 4 frags x 64 x 8
  float *bq1F, *bpF, *bk1F;                          // 64 fp32 each
};

__device__ __forceinline__ unsigned short f2bf(float x){
  __hip_bfloat16 h = __float2bfloat16(x);
  unsigned short u; __builtin_memcpy(&u, &h, 2); return u;
}
__device__ __forceinline__ float bf2f(unsigned short s){
  union{unsigned u; float f;} c; c.u = ((unsigned)s) << 16; return c.f;
}
__device__ __forceinline__ unsigned pk2(float x, float y){
  __hip_bfloat162 h = __float22bfloat162_rn(make_float2(x, y));
  unsigned u; __builtin_memcpy(&u, &h, 4); return u;
}
__device__ __forceinline__ s8v pack8(f4v x0, f4v x1){
  s8v r;
  ((unsigned*)&r)[0] = pk2(x0[0], x0[1]);
  ((unsigned*)&r)[1] = pk2(x0[2], x0[3]);
  ((unsigned*)&r)[2] = pk2(x1[0], x1[1]);
  ((unsigned*)&r)[3] = pk2(x1[2], x1[3]);
  return r;
}

// ---------------- prep: BN folds + fused k@W1 + B-fragment swizzles -------
__global__ void __launch_bounds__(256) prep_kernel(InP P, WS W){
  const int g = blockIdx.x*256 + threadIdx.x;   // 0..4095
  const int e = g >> 3, j = g & 7;              // e < 512
  const int f = e >> 6, L = e & 63;
  const int ks = f & 1, nt = f >> 1;
  const int n = nt*16 + (L & 15);
  const int k = ks*32 + ((L >> 4) << 3) + j;
  const float sg = P.bng_g[n] * rsqrtf(P.bng_v[n] + EPSV);
  W.W1f[e*8+j] = f2bf(P.Wg1[k*64+n] * sg);
  W.W2f[e*8+j] = f2bf(P.Wg2[k*64+n]);
  W.Wof[e*8+j] = f2bf(P.Wo [k*64+n]);
  W.Wvf[e*8+j] = f2bf(P.Wv [k*64+n]);
  float acc = 0.f, acck = 0.f;
  #pragma unroll 8
  for (int d = 0; d < 64; d++){
    float w1 = P.Wg1[d*64+n];
    acc  += P.Wq[k*64+d] * w1;
    acck += P.Wk[k*64+d] * w1;
  }
  W.WAf[e*8+j] = f2bf(acc  * sg);   // Wq@W1F (BN-scaled)
  W.Wkf[e*8+j] = f2bf(acck * sg);   // Wk@W1F (BN-scaled) -- fused
  if (g < 2048){
    int ep = g >> 3;  // 0..255
    int ntp = ep >> 6, Lp = ep & 63;
    int np_ = ntp*16 + (Lp & 15);
    int kp = ((Lp >> 4) << 3) + j;
    float sp = P.bnp_g[np_] * rsqrtf(P.bnp_v[np_] + EPSV);
    W.Wpf[ep*8+j] = f2bf(kp < 3 ? P.Wp[kp*64+np_]*sp : 0.f);
  }
  if (g < 64){
    float sgt = P.bng_g[g] * rsqrtf(P.bng_v[g] + EPSV);
    float spt = P.bnp_g[g] * rsqrtf(P.bnp_v[g] + EPSV);
    float acc2 = 0.f, acck2 = 0.f;
    for (int d = 0; d < 64; d++){
      float w1 = P.Wg1[d*64+g];
      acc2  += P.bq[d] * w1;
      acck2 += P.bk[d] * w1;
    }
    // qW1 bias carries ALL of b1F (bg1 + BN offset); kW1 bias only bk@W1F
    W.bq1F[g] = acc2*sgt + P.bg1[g]*sgt + P.bng_b[g] - P.bng_m[g]*sgt;
    W.bk1F[g] = acck2*sgt;
    W.bpF[g]  = P.b_p[g]*spt + P.bnp_b[g] - P.bnp_m[g]*spt;
  }
}

// ---- qkv: qW1 = f@(Wq@W1F)+bq1F ; kvT = [f@(Wk@W1F)+bk1F | f@Wv+bv] ----
__global__ void __launch_bounds__(256) qkv_kernel(InP P, WS W){
  const int tid = threadIdx.x;
  const int wid = tid >> 6, l = tid & 63;
  const int cl = l & 15, q = l >> 4;
  const int TILES = (P.N + 15) >> 4;
  const int task = blockIdx.x * TW + wid;
  if (task >= TILES) return;
  const int i0 = task * 16;
  int row = i0 + cl; if (row > P.N - 1) row = P.N - 1;
  const float* fr = P.features + (size_t)row*64 + q*8;
  f4v x0 = *(const f4v*)fr;
  f4v x1 = *(const f4v*)(fr + 4);
  s8v fa0 = pack8(x0, x1);
  x0 = *(const f4v*)(fr + 32);
  x1 = *(const f4v*)(fr + 36);
  s8v fa1 = pack8(x0, x1);

  auto doMat = [&](const unsigned short* Bf_, const float* biasPtr,
                   unsigned short* outPtr, int stride){
    const s8v* Bf = (const s8v*)Bf_;
    #pragma unroll
    for (int nt = 0; nt < 4; nt++){
      float bn = biasPtr[nt*16 + cl];
      f4v ci = { bn, bn, bn, bn };
      f4v c = __builtin_amdgcn_mfma_f32_16x16x32_bf16(fa0, Bf[(2*nt+0)*64 + l], ci, 0, 0, 0);
      c = __builtin_amdgcn_mfma_f32_16x16x32_bf16(fa1, Bf[(2*nt+1)*64 + l], c, 0, 0, 0);
      #pragma unroll
      for (int r = 0; r < 4; r++){
        int rg = i0 + q*4 + r;
        if (rg < P.N) outPtr[(size_t)rg*stride + nt*16 + cl] = f2bf(c[r]);
      }
    }
  };
  doMat(W.WAf, W.bq1F, W.qW1,      64);
  doMat(W.Wkf, W.bk1F, W.kvT,     128);
  doMat(W.Wvf, P.bv,   W.kvT + 64,128);
}

// ---------------- main: 8-pt tiles, fused k@W1 C-init, parity-dbuf Sp -----
// Per-wave LDS (wave-private, no __syncthreads):
//   Sp  [2][16][SPD] bf16 : p / T transpose scratch, parity double-buffered
//   PreB[TPW][SPD] bf16   : pre rows for inline Wo epilogue
//   sI  [TPW*16] int      : tile neighbor indices
// kW1 and v both gathered in C-layout from the SAME kvT row (one base/row).
// GEMM1 A-operand is pure p (direct s8v LDS read, no subtraction).
// NOTE (R9): natural VGPR ~110; forcing min-waves>2 spills catastrophically.
__global__ void __launch_bounds__(256, 2) main_kernel(InP P, WS W){
  __shared__ __align__(16) unsigned short Sp[TW][2][16*SPD];
  __shared__ __align__(16) unsigned short PreB[TW][TPW*SPD];
  __shared__ __align__(16) int sI[TW][TPW*16];
  const int tid = threadIdx.x;
  const int wid = tid >> 6, l = tid & 63;
  const int cl = l & 15, q = l >> 4;
  const int TILES = (P.N + TPW - 1) / TPW;
  const int task = blockIdx.x * TW + wid;
  if (task >= TILES) return;
  const int i0 = task * TPW;
  unsigned short* PreBw = PreB[wid];
  int* sIw = sI[wid];

  // cooperative neighbor-index stage (TPW*16 = 128 ints per tile, 2/lane)
  {
    long base = (long)i0*16 + l*2;
    long maxb = (long)P.N*16 - 2;
    if (base > maxb) base = maxb;
    int2 gi = *(const int2*)(P.gidx + base);
    *(int2*)&sIw[l*2] = gi;
  }

  // held B-frags: W1 (BN-folded), W2, Wp
  s8v w1f[8], w2f[8], wpf[4];
  {
    const s8v* W1p = (const s8v*)W.W1f;
    const s8v* W2p = (const s8v*)W.W2f;
    const s8v* Wpp = (const s8v*)W.Wpf;
    #pragma unroll
    for (int f = 0; f < 8; f++){ w1f[f] = W1p[f*64 + l]; w2f[f] = W2p[f*64 + l]; }
    #pragma unroll
    for (int f = 0; f < 4; f++) wpf[f] = Wpp[f*64 + l];
  }
  float bp4[4], b24[4];
  #pragma unroll
  for (int nt = 0; nt < 4; nt++){ bp4[nt] = W.bpF[nt*16 + cl]; b24[nt] = P.bg2[nt*16 + cl]; }

  // ---- prologue prefetch for pt = 0 (neighbor xyz, center, qW1 row)
  float ngx=0.f, ngy=0.f, ngz=0.f;
  {
    int nidx = sIw[cl];
    if (l < 16){ const float* gp = P.points + (size_t)nidx*3; ngx=gp[0]; ngy=gp[1]; ngz=gp[2]; }
  }
  float ncx = P.points[(size_t)i0*3+0];
  float ncy = P.points[(size_t)i0*3+1];
  float ncz = P.points[(size_t)i0*3+2];
  float nq0, nq1, nq2, nq3;
  {
    const unsigned short* qr = W.qW1 + (size_t)i0*64;
    nq0 = bf2f(qr[cl]); nq1 = bf2f(qr[16+cl]); nq2 = bf2f(qr[32+cl]); nq3 = bf2f(qr[48+cl]);
  }

  #pragma unroll 2
  for (int pt = 0; pt < TPW; pt++){
    unsigned short* Spw = Sp[wid][pt & 1];
    // rotate prefetch -> current
    float gx=ngx, gy=ngy, gz=ngz, cx=ncx, cy=ncy, cz=ncz;
    float qcn4[4] = { nq0, nq1, nq2, nq3 };
    const bool valid = (i0 + pt < P.N);

    // 1. issue kW1 + v gathers for CURRENT point in C-layout (same rows!)
    //    lane (cl,q): rows vidx[r] (r=0..3); kw consumed at GEMM1 C-init,
    //    vv consumed in phase 8.
    unsigned short kw[16], vv[16];
    {
      int4 vidx = *(const int4*)&sIw[pt*16 + q*4];
      #pragma unroll
      for (int r = 0; r < 4; r++){
        const unsigned short* vb = W.kvT + (size_t)vidx[r]*128 + cl;
        #pragma unroll
        for (int nt = 0; nt < 4; nt++){
          kw[nt*4+r] = vb[nt*16];
          vv[nt*4+r] = vb[64 + nt*16];
        }
      }
    }

    // 2. p = relu(rel @ WpF + bpF), write to Sp (C-layout, bf16 scalar)
    s8v ap;
    ((unsigned*)&ap)[0] = pk2(gx-cx, gy-cy);
    ((unsigned*)&ap)[1] = pk2(gz-cz, 0.f);
    ((unsigned*)&ap)[2] = 0u; ((unsigned*)&ap)[3] = 0u;
    f4v pc[4];
    #pragma unroll
    for (int nt = 0; nt < 4; nt++){
      f4v ci = { bp4[nt], bp4[nt], bp4[nt], bp4[nt] };
      pc[nt] = __builtin_amdgcn_mfma_f32_16x16x32_bf16(ap, wpf[nt], ci, 0, 0, 0);
    }
    #pragma unroll
    for (int nt = 0; nt < 4; nt++){
      #pragma unroll
      for (int r = 0; r < 4; r++){
        pc[nt][r] = fmaxf(pc[nt][r], 0.f);
        Spw[(q*4+r)*SPD + nt*16 + cl] = f2bf(pc[nt][r]);
      }
    }

    // 3. prefetch pt+1 (wraps harmlessly at pt=TPW-1)
    {
      int np = (pt + 1) & (TPW-1);
      int nidx = sIw[np*16 + cl];
      if (l < 16){ const float* gp = P.points + (size_t)nidx*3; ngx=gp[0]; ngy=gp[1]; ngz=gp[2]; }
      int ii = i0 + np; if (ii > P.N - 1) ii = P.N - 1;
      ncx = P.points[(size_t)ii*3+0];
      ncy = P.points[(size_t)ii*3+1];
      ncz = P.points[(size_t)ii*3+2];
      const unsigned short* qr = W.qW1 + (size_t)ii*64;
      nq0 = bf2f(qr[cl]); nq1 = bf2f(qr[16+cl]); nq2 = bf2f(qr[32+cl]); nq3 = bf2f(qr[48+cl]);
    }

    // 4. read p back as A-frags (no subtraction -- k@W1 folded into C-init)
    s8v af0 = *(const s8v*)&Spw[cl*SPD + q*8];
    s8v af1 = *(const s8v*)&Spw[cl*SPD + 32 + q*8];

    // 5. T = relu(p @ W1F + (qW1row - kW1row))
    f4v tc[4];
    #pragma unroll
    for (int nt = 0; nt < 4; nt++){
      f4v ci = { qcn4[nt] - bf2f(kw[nt*4+0]),
                 qcn4[nt] - bf2f(kw[nt*4+1]),
                 qcn4[nt] - bf2f(kw[nt*4+2]),
                 qcn4[nt] - bf2f(kw[nt*4+3]) };
      tc[nt] = __builtin_amdgcn_mfma_f32_16x16x32_bf16(af0, w1f[2*nt+0], ci, 0, 0, 0);
      tc[nt] = __builtin_amdgcn_mfma_f32_16x16x32_bf16(af1, w1f[2*nt+1], tc[nt], 0, 0, 0);
      #pragma unroll
      for (int r = 0; r < 4; r++) tc[nt][r] = fmaxf(tc[nt][r], 0.f);
    }

    // 6. T -> Sp (bf16 scalar C-write), read back directly as A-frags
    #pragma unroll
    for (int nt = 0; nt < 4; nt++)
      #pragma unroll
      for (int r = 0; r < 4; r++)
        Spw[(q*4+r)*SPD + nt*16 + cl] = f2bf(tc[nt][r]);
    s8v tf0 = *(const s8v*)&Spw[cl*SPD + q*8];
    s8v tf1 = *(const s8v*)&Spw[cl*SPD + 32 + q*8];

    // 7. H = T @ W2 + b2
    f4v hc[4];
    #pragma unroll
    for (int nt = 0; nt < 4; nt++){
      f4v ci = { b24[nt], b24[nt], b24[nt], b24[nt] };
      hc[nt] = __builtin_amdgcn_mfma_f32_16x16x32_bf16(tf0, w2f[2*nt+0], ci, 0, 0, 0);
      hc[nt] = __builtin_amdgcn_mfma_f32_16x16x32_bf16(tf1, w2f[2*nt+1], hc[nt], 0, 0, 0);
    }

    // 8. softmax over 16 neighbor rows (no max-shift: |h| small, exp safe)
    //    + weighted sum of (v+p)
    float pre4[4];
    #pragma unroll
    for (int nt = 0; nt < 4; nt++){
      float s = 0.f, acc = 0.f;
      #pragma unroll
      for (int r = 0; r < 4; r++){
        float e2 = __expf(hc[nt][r]);
        s += e2;
        acc = fmaf(e2, bf2f(vv[nt*4+r]) + pc[nt][r], acc);
      }
      s += __shfl_xor(s, 16, 64);
      s += __shfl_xor(s, 32, 64);
      acc += __shfl_xor(acc, 16, 64);
      acc += __shfl_xor(acc, 32, 64);
      pre4[nt] = acc * __builtin_amdgcn_rcpf(s);
    }
    if (valid){
      float sa = (l & 16) ? pre4[1] : pre4[0];
      float sb = (l & 16) ? pre4[3] : pre4[2];
      PreBw[pt*SPD + l] = f2bf((l & 32) ? sb : sa);
    }
  }

  // inline epilogue: out rows = PreB(8x64) @ Wo + bo (rows 8..15 duplicated,
  // discarded by the store guard)
  s8v wof[8];
  {
    const s8v* Wop = (const s8v*)W.Wof;
    #pragma unroll
    for (int f = 0; f < 8; f++) wof[f] = Wop[f*64 + l];
  }
  s8v ef0 = *(const s8v*)&PreBw[(cl & (TPW-1))*SPD + q*8];
  s8v ef1 = *(const s8v*)&PreBw[(cl & (TPW-1))*SPD + 32 + q*8];
  #pragma unroll
  for (int nt = 0; nt < 4; nt++){
    float bn = P.bo[nt*16 + cl];
    f4v ci = { bn, bn, bn, bn };
    f4v oc = __builtin_amdgcn_mfma_f32_16x16x32_bf16(ef0, wof[2*nt+0], ci, 0, 0, 0);
    oc = __builtin_amdgcn_mfma_f32_16x16x32_bf16(ef1, wof[2*nt+1], oc, 0, 0, 0);
    #pragma unroll
    for (int r = 0; r < 4; r++){
      int ro = q*4 + r;
      int rg = i0 + ro;
      if (ro < TPW && rg < P.N) P.out[(size_t)rg*64 + nt*16 + cl] = oc[r];
    }
  }
}

extern "C" void kernel_launch(void* const* d_in, const int* in_sizes, int n_in,
                              void* d_out, int out_size, void* d_ws, size_t ws_size,
                              hipStream_t stream){
  InP P;
  P.points   = (const float*)d_in[0];
  P.features = (const float*)d_in[1];
  P.gidx     = (const int*)d_in[2];
  P.Wq  = (const float*)d_in[3];  P.bq  = (const float*)d_in[4];
  P.Wk  = (const float*)d_in[5];  P.bk  = (const float*)d_in[6];
  P.Wv  = (const float*)d_in[7];  P.bv  = (const float*)d_in[8];
  P.Wp  = (const float*)d_in[9];  P.b_p = (const float*)d_in[10];
  P.bnp_g = (const float*)d_in[11]; P.bnp_b = (const float*)d_in[12];
  P.bnp_m = (const float*)d_in[13]; P.bnp_v = (const float*)d_in[14];
  P.Wg1 = (const float*)d_in[15]; P.bg1 = (const float*)d_in[16];
  P.bng_g = (const float*)d_in[17]; P.bng_b = (const float*)d_in[18];
  P.bng_m = (const float*)d_in[19]; P.bng_v = (const float*)d_in[20];
  P.Wg2 = (const float*)d_in[21]; P.bg2 = (const float*)d_in[22];
  P.Wo  = (const float*)d_in[23]; P.bo  = (const float*)d_in[24];
  P.out = (float*)d_out;
  const int N = in_sizes[0] / 3;
  P.N = N;

  WS W;
  char* w = (char*)d_ws;
  W.qW1 = (unsigned short*)w; w += (size_t)N*64*2;
  W.kvT = (unsigned short*)w; w += (size_t)N*128*2;
  W.WAf = (unsigned short*)w; w += 8*64*8*2;
  W.Wkf = (unsigned short*)w; w += 8*64*8*2;
  W.Wvf = (unsigned short*)w; w += 8*64*8*2;
  W.W1f = (unsigned short*)w; w += 8*64*8*2;
  W.W2f = (unsigned short*)w; w += 8*64*8*2;
  W.Wof = (unsigned short*)w; w += 8*64*8*2;
  W.Wpf = (unsigned short*)w; w += 4*64*8*2;
  W.bq1F = (float*)w; w += 256;
  W.bpF  = (float*)w; w += 256;
  W.bk1F = (float*)w; w += 256;

  const int TILES16 = (N + 15) / 16;
  const int grid16 = (TILES16 + TW - 1) / TW;
  const int TILESM = (N + TPW - 1) / TPW;
  const int gridM = (TILESM + TW - 1) / TW;
  hipLaunchKernelGGL(prep_kernel, dim3(16),     dim3(256), 0, stream, P, W);
  hipLaunchKernelGGL(qkv_kernel,  dim3(grid16), dim3(256), 0, stream, P, W);
  hipLaunchKernelGGL(main_kernel, dim3(gridM),  dim3(256), 0, stream, P, W);
}